// Round 15
// baseline (176.296 us; speedup 1.0000x reference)
//
#include <hip/hip_runtime.h>
#include <hip/hip_cooperative_groups.h>

namespace cg = cooperative_groups;

#define NB 16384
#define NDOM 10
#define HIDN 512
#define STYLE 64

typedef short bf16x8 __attribute__((ext_vector_type(8)));
typedef float f32x16 __attribute__((ext_vector_type(16)));

#define MFMA __builtin_amdgcn_mfma_f32_32x32x16_bf16

// ---------------- bf16 helpers ----------------

__device__ __forceinline__ unsigned bfr_hi(float x) {
    unsigned u = __float_as_uint(x);
    return (u + 0x7fffu + ((u >> 16) & 1u)) & 0xffff0000u;  // RNE bf16 in high bits
}

__device__ __forceinline__ unsigned cvtpk(float a, float b) {
    unsigned r;
    asm("v_cvt_pk_bf16_f32 %0, %1, %2" : "=v"(r) : "v"(a), "v"(b));
    return r;   // [15:0]=bf16(a), [31:16]=bf16(b)
}

__device__ __forceinline__ void cvhalf2(const float4& x, const float4& y, uint4& h, uint4& l) {
    float xs[8] = {x.x, x.y, x.z, x.w, y.x, y.y, y.z, y.w};
    unsigned hh[8], ll[8];
#pragma unroll
    for (int i = 0; i < 8; ++i) {
        unsigned hb = bfr_hi(xs[i]);
        hh[i] = hb;
        ll[i] = bfr_hi(xs[i] - __uint_as_float(hb));
    }
    h = make_uint4((hh[0] >> 16) | (hh[1] & 0xffff0000u), (hh[2] >> 16) | (hh[3] & 0xffff0000u),
                   (hh[4] >> 16) | (hh[5] & 0xffff0000u), (hh[6] >> 16) | (hh[7] & 0xffff0000u));
    l = make_uint4((ll[0] >> 16) | (ll[1] & 0xffff0000u), (ll[2] >> 16) | (ll[3] & 0xffff0000u),
                   (ll[4] >> 16) | (ll[5] & 0xffff0000u), (ll[6] >> 16) | (ll[7] & 0xffff0000u));
}

struct KParams {
    const float* z; const int* y;
    const float* W0; const float* b0; const float* W1; const float* b1;
    const float* W2; const float* b2; const float* W3; const float* b3;
    const float* Wu1; const float* bu1; const float* Wu2; const float* bu2;
    const float* Wu3; const float* bu3; const float* Wo; const float* bo;
    short* Wp; short* W0p; short* WoP;
    int* rowidx; int* partial;
    float* out;
};

// ---------------- P3 helpers (round-14 proven k-loop) ----------------
// Wave w (0..15) owns outcols [32w,32w+32); rows = nf*32 + (lane&31).
// h LDS (hi-only bf16): octet o=k>>3, idx = o*512 + row*8 shorts, 16B/line.
// Operand-swapped MFMA: A = weights (m=outcol), B = activations (n=batchrow).

template<int NFM>
__device__ __forceinline__ void pass512(const short* __restrict__ sH,
                                        const short* __restrict__ pW,
                                        int w, int lane, f32x16 acc[2])
{
#pragma unroll
    for (int nf = 0; nf < 2; ++nf)
        if (NFM & (1 << nf))
#pragma unroll
            for (int e = 0; e < 16; ++e) acc[nf][e] = 0.f;
    const int rb = (lane & 31) * 8;
    const int lh = lane >> 5;
    const short* p = pW + (w >> 1) * 32768 + (w & 1) * 512 + lane * 8;
    bf16x8 wv[4];
#pragma unroll
    for (int d = 0; d < 4; ++d) wv[d] = *(const bf16x8*)(p + d * 1024);
    bf16x8 hb[2][2];
    const int base0 = lh * 512 + rb;
#pragma unroll
    for (int nf = 0; nf < 2; ++nf)
        if (NFM & (1 << nf)) hb[0][nf] = *(const bf16x8*)(sH + base0 + nf * 256);
#pragma unroll
    for (int ks = 0; ks < 32; ++ks) {
        const int pc = ks & 1, pn = pc ^ 1;
        bf16x8 wk = wv[ks & 3];
        if (ks < 28) wv[ks & 3] = *(const bf16x8*)(p + (ks + 4) * 1024);
        if (ks < 31) {
            const int basen = (2 * (ks + 1) + lh) * 512 + rb;
#pragma unroll
            for (int nf = 0; nf < 2; ++nf)
                if (NFM & (1 << nf)) hb[pn][nf] = *(const bf16x8*)(sH + basen + nf * 256);
        }
#pragma unroll
        for (int nf = 0; nf < 2; ++nf)
            if (NFM & (1 << nf)) acc[nf] = MFMA(wk, hb[pc][nf], acc[nf], 0, 0, 0);
    }
}

template<int NFM, bool RELU>
__device__ __forceinline__ void epi512(short* __restrict__ sH, f32x16 acc[2],
                                       const float* __restrict__ bias,
                                       int w, int lane, int rlo, int rhi)
{
    const int lh = lane >> 5;
#pragma unroll
    for (int nf = 0; nf < 2; ++nf) {
        if (!(NFM & (1 << nf))) continue;
        const int row = nf * 32 + (lane & 31);
        const bool pred = (row >= rlo && row < rhi);
        unsigned mh[4][2];
#pragma unroll
        for (int q = 0; q < 4; ++q) {
            const float4 bv = *(const float4*)&bias[w * 32 + q * 8 + lh * 4];
            float v[4];
#pragma unroll
            for (int j = 0; j < 4; ++j) {
                float x = acc[nf][q * 4 + j] + (&bv.x)[j];
                if (RELU) x = fmaxf(x, 0.f);
                v[j] = x;
            }
            mh[q][0] = cvtpk(v[0], v[1]);
            mh[q][1] = cvtpk(v[2], v[3]);
        }
#pragma unroll
        for (int t = 0; t < 2; ++t) {
            const int q = 2 * t + lh;
            const int qs = 2 * t + (lh ^ 1);
            unsigned r0 = (unsigned)__shfl_xor((int)mh[qs][0], 32);
            unsigned r1 = (unsigned)__shfl_xor((int)mh[qs][1], 32);
            uint4 line = lh == 0 ? make_uint4(mh[q][0], mh[q][1], r0, r1)
                                 : make_uint4(r0, r1, mh[q][0], mh[q][1]);
            if (pred) *(uint4*)(sH + (w * 4 + q) * 512 + row * 8) = line;
        }
    }
}

// ---------------- the cooperative mega-kernel ----------------
// 256 blocks x 1024 threads. P1: weight prep + hist partials (291 tasks,
// 1-2 per block). grid.sync. P2: deterministic rank-based scatter (16 blocks).
// grid.sync. P3: fused network (round-14 body).

__global__ __launch_bounds__(1024, 4)
void k_all(KParams P)
{
    __shared__ __align__(16) short sH[32768];   // 64 KiB; P1 aliases as f32 Ld[64][68]
    __shared__ int scnt[16][NDOM];
    __shared__ int sbase[16][NDOM];
    __shared__ int sAux[NDOM + 1];
    __shared__ int sPfx[NDOM];
    __shared__ int soff[NDOM + 1];

    const int tid = threadIdx.x;
    const int lane = tid & 63;
    const int w = tid >> 6;      // 0..15
    const int lh = lane >> 5;
    const int bid = blockIdx.x;

    // ================= P1: weight prep + histogram partials =================
    float* Ld = (float*)sH;      // [64][68] (272B rows, 16B aligned)
    for (int task = bid; task < 291; task += 256) {
        __syncthreads();
        if (task < 264) {
            // big mats: 0..2 = W1..W3 ; 3+d = Wu1 ; 13+d = Wu2 ; 23+d = Wu3
            const int mat = task >> 3, wq = task & 7;
            const float* src;
            if (mat < 3) src = (mat == 0 ? P.W1 : (mat == 1 ? P.W2 : P.W3));
            else {
                int g = (mat - 3) / 10, d = (mat - 3) % 10;
                src = (g == 0 ? P.Wu1 : (g == 1 ? P.Wu2 : P.Wu3)) + (size_t)d * HIDN * HIDN;
            }
            short* dst = P.Wp + (size_t)mat * 262144 + wq * 32768;
            for (int s = 0; s < 8; ++s) {
                {   // 64x64 f32 tile, 1 float4 per thread
                    int row = tid >> 4, c4 = tid & 15;
                    *(float4*)&Ld[row * 68 + c4 * 4] =
                        *(const float4*)(src + (size_t)(s * 64 + row) * HIDN + wq * 64 + c4 * 4);
                }
                __syncthreads();
                if (tid < 512) {
                    int g = tid;
                    int ksl = g >> 7, of = (g >> 6) & 1, k8 = (g >> 5) & 1, c5 = g & 31;
                    int kk = ksl * 16 + k8 * 8;
                    unsigned pk[4];
#pragma unroll
                    for (int j2 = 0; j2 < 4; ++j2) {
                        unsigned h0 = bfr_hi(Ld[(kk + 2 * j2) * 68 + of * 32 + c5]);
                        unsigned h1 = bfr_hi(Ld[(kk + 2 * j2 + 1) * 68 + of * 32 + c5]);
                        pk[j2] = (h0 >> 16) | (h1 & 0xffff0000u);
                    }
                    *(uint4*)(dst + (s * 4 + ksl) * 1024 + of * 512 + k8 * 256 + c5 * 8) =
                        make_uint4(pk[0], pk[1], pk[2], pk[3]);
                }
                __syncthreads();
            }
        } else if (task == 264) {
            // W0 (16x512): granule g = tid
            int g = tid;
            int wq = g >> 7, of = (g >> 6) & 1, k8 = (g >> 5) & 1, c5 = g & 31;
            int col = wq * 64 + of * 32 + c5;
            unsigned pk[4];
#pragma unroll
            for (int j2 = 0; j2 < 4; ++j2) {
                unsigned h0 = bfr_hi(P.W0[(size_t)(k8 * 8 + 2 * j2) * HIDN + col]);
                unsigned h1 = bfr_hi(P.W0[(size_t)(k8 * 8 + 2 * j2 + 1) * HIDN + col]);
                pk[j2] = (h0 >> 16) | (h1 & 0xffff0000u);
            }
            *(uint4*)(P.W0p + g * 8) = make_uint4(pk[0], pk[1], pk[2], pk[3]);
        } else if (task < 275) {
            // Wo (per dom 512x64): 4096 granules, 4 per thread
            const int dom = task - 265;
            const float* src = P.Wo + (size_t)dom * HIDN * STYLE;
            short* dst = P.WoP + (size_t)dom * 32768;
#pragma unroll
            for (int i = 0; i < 4; ++i) {
                int g = i * 1024 + tid;
                int w1 = g >> 11, ks = (g >> 6) & 31, k8 = (g >> 5) & 1, c5 = g & 31;
                int col = w1 * 32 + c5;
                int k0 = ks * 16 + k8 * 8;
                unsigned pk[4];
#pragma unroll
                for (int j2 = 0; j2 < 4; ++j2) {
                    unsigned h0 = bfr_hi(src[(size_t)(k0 + 2 * j2) * STYLE + col]);
                    unsigned h1 = bfr_hi(src[(size_t)(k0 + 2 * j2 + 1) * STYLE + col]);
                    pk[j2] = (h0 >> 16) | (h1 & 0xffff0000u);
                }
                *(uint4*)(dst + g * 8) = make_uint4(pk[0], pk[1], pk[2], pk[3]);
            }
        } else {
            // histogram chunk (1024 rows), per-chunk partial counts (no atomics)
            const int chunk = task - 275;
            const int d = P.y[chunk * 1024 + tid];
#pragma unroll
            for (int dd = 0; dd < NDOM; ++dd) {
                unsigned long long bal = __ballot(d == dd);
                if (lane == 0) scnt[w][dd] = (int)__popcll(bal);
            }
            __syncthreads();
            if (tid < NDOM) {
                int tot = 0;
#pragma unroll
                for (int c = 0; c < 16; ++c) tot += scnt[c][tid];
                P.partial[chunk * NDOM + tid] = tot;
            }
        }
    }

    cg::this_grid().sync();

    // ================= P2: deterministic rank-based scatter =================
    if (bid < 16) {
        const int chunk = bid;
        if (tid < NDOM) {
            int tot = 0, pfx = 0;
            for (int c = 0; c < 16; ++c) {
                int v = P.partial[c * NDOM + tid];
                if (c < chunk) pfx += v;
                tot += v;
            }
            sAux[tid] = tot; sPfx[tid] = pfx;
        }
        __syncthreads();
        const int i = chunk * 1024 + tid;
        const int d = P.y[i];
        const unsigned long long below = (1ULL << lane) - 1ULL;
        int rnk = 0;
#pragma unroll
        for (int dd = 0; dd < NDOM; ++dd) {
            unsigned long long bal = __ballot(d == dd);
            if (d == dd) rnk = (int)__popcll(bal & below);
            if (lane == 0) scnt[w][dd] = (int)__popcll(bal);
        }
        if (tid == 0) {
            int s = 0;
            for (int dd = 0; dd < NDOM; ++dd) { int t2 = sAux[dd]; sAux[dd] = s; s += t2; }
        }
        __syncthreads();
        if (tid < NDOM) {
            int s = 0;
            for (int c = 0; c < 16; ++c) { sbase[c][tid] = s; s += scnt[c][tid]; }
        }
        __syncthreads();
        P.rowidx[sAux[d] + sPfx[d] + sbase[w][d] + rnk] = i;
    }

    cg::this_grid().sync();

    // ================= P3: fused network (round-14 body) =================
    // XCD-chunked bijective swizzle: neighbors share a domain -> L2 reuse
    const int win = (bid & 7) * 32 + (bid >> 3);
    const int row0 = win * 64;

    if (tid < NDOM) {
        int tot = 0;
        for (int c = 0; c < 16; ++c) tot += P.partial[c * NDOM + tid];
        sAux[tid] = tot;
    }
    __syncthreads();
    if (tid == 0) {
        int s = 0;
#pragma unroll
        for (int dd = 0; dd < NDOM; ++dd) { soff[dd] = s; s += sAux[dd]; }
        soff[NDOM] = s;
    }
    // soff first read in the head loop — multiple __syncthreads before then

    f32x16 acc[2];

    // ---- layer 0: z (K=16) -> h (z itself split hi/lo; out hi-only) ----
    {
        bf16x8 w0v = *(const bf16x8*)(P.W0p + (w >> 1) * 1024 + (w & 1) * 512 + lane * 8);
#pragma unroll
        for (int nf = 0; nf < 2; ++nf) {
#pragma unroll
            for (int e = 0; e < 16; ++e) acc[nf][e] = 0.f;
            const int r = nf * 32 + (lane & 31);
            const int src = P.rowidx[row0 + r];
            const float* zp = P.z + (size_t)src * 16 + lh * 8;
            float4 f0 = *(const float4*)zp;
            float4 f1 = *(const float4*)(zp + 4);
            uint4 h, l;
            cvhalf2(f0, f1, h, l);
            bf16x8 zh = *(bf16x8*)&h;
            bf16x8 zl = *(bf16x8*)&l;
            acc[nf] = MFMA(w0v, zh, acc[nf], 0, 0, 0);
            acc[nf] = MFMA(w0v, zl, acc[nf], 0, 0, 0);
        }
        epi512<3, true>(sH, acc, P.b0, w, lane, 0, 64);
        __syncthreads();
    }

    // ---- trunk layers 1-3 ----
#pragma unroll 1
    for (int m = 0; m < 3; ++m) {
        const float* bp = (m == 0) ? P.b1 : (m == 1) ? P.b2 : P.b3;
        pass512<3>(sH, P.Wp + (size_t)m * 262144, w, lane, acc);
        __syncthreads();
        epi512<3, true>(sH, acc, bp, w, lane, 0, 64);
        __syncthreads();
    }

    // ---- head layers: per-domain, nf-granular (32-row groups) ----
#pragma unroll 1
    for (int L = 0; L < 3; ++L) {
        const short* WL_ = P.Wp + (size_t)(3 + L * 10) * 262144;
        const float* bL = (L == 0) ? P.bu1 : (L == 1) ? P.bu2 : P.bu3;
#pragma unroll 1
        for (int d = 0; d < NDOM; ++d) {
            int rlo = soff[d] - row0, rhi = soff[d + 1] - row0;
            rlo = rlo < 0 ? 0 : rlo;
            rhi = rhi > 64 ? 64 : rhi;
            if (rhi <= rlo) continue;
            const int nfm = (rlo < 32 ? 1 : 0) | (rhi > 32 ? 2 : 0);
            const short* pw = WL_ + (size_t)d * 262144;
            if (nfm == 3)      pass512<3>(sH, pw, w, lane, acc);
            else if (nfm == 1) pass512<1>(sH, pw, w, lane, acc);
            else               pass512<2>(sH, pw, w, lane, acc);
            __syncthreads();
            if (nfm == 3)      epi512<3, true>(sH, acc, bL + d * HIDN, w, lane, rlo, rhi);
            else if (nfm == 1) epi512<1, true>(sH, acc, bL + d * HIDN, w, lane, rlo, rhi);
            else               epi512<2, true>(sH, acc, bL + d * HIDN, w, lane, rlo, rhi);
            __syncthreads();
        }
    }

    // ---- final 512->64: 4 waves, wave = (row-half, col-half) tile ----
    if (w < 4) {
        const int rh = w >> 1, ch = w & 1;
        const int r = rh * 32 + (lane & 31);
#pragma unroll 1
        for (int d = 0; d < NDOM; ++d) {
            int rlo = soff[d] - row0, rhi = soff[d + 1] - row0;
            rlo = rlo < 0 ? 0 : rlo;
            rhi = rhi > 64 ? 64 : rhi;
            if (rhi <= rlo) continue;
            if (rhi <= rh * 32 || rlo >= rh * 32 + 32) continue;
            f32x16 fa;
#pragma unroll
            for (int e = 0; e < 16; ++e) fa[e] = 0.f;
            const short* pw = P.WoP + (size_t)d * 32768 + ch * 16384 + lane * 8;
            bf16x8 wb[4];
#pragma unroll
            for (int dd = 0; dd < 4; ++dd) wb[dd] = *(const bf16x8*)(pw + dd * 512);
            const int hbase = (rh * 32 + (lane & 31)) * 8;
#pragma unroll
            for (int ks = 0; ks < 32; ++ks) {
                bf16x8 wk = wb[ks & 3];
                if (ks < 28) wb[ks & 3] = *(const bf16x8*)(pw + (ks + 4) * 512);
                bf16x8 bhv = *(const bf16x8*)(sH + (2 * ks + lh) * 512 + hbase);
                fa = MFMA(wk, bhv, fa, 0, 0, 0);
            }
            if (r >= rlo && r < rhi) {
                const int orow = P.rowidx[row0 + r];
                float* op = P.out + (size_t)orow * STYLE + ch * 32 + lh * 4;
                const float* bop = P.bo + d * STYLE + ch * 32 + lh * 4;
#pragma unroll
                for (int q = 0; q < 4; ++q) {
                    float4 v;
                    v.x = fa[q * 4 + 0] + bop[q * 8 + 0];
                    v.y = fa[q * 4 + 1] + bop[q * 8 + 1];
                    v.z = fa[q * 4 + 2] + bop[q * 8 + 2];
                    v.w = fa[q * 4 + 3] + bop[q * 8 + 3];
                    *(float4*)(op + q * 8) = v;
                }
            }
        }
    }
}

// ---------------- launch ----------------

extern "C" void kernel_launch(void* const* d_in, const int* in_sizes, int n_in,
                              void* d_out, int out_size, void* d_ws, size_t ws_size,
                              hipStream_t stream) {
    KParams prm;
    prm.z   = (const float*)d_in[0];
    prm.y   = (const int*)d_in[1];
    prm.W0  = (const float*)d_in[2];
    prm.b0  = (const float*)d_in[3];
    prm.W1  = (const float*)d_in[4];
    prm.b1  = (const float*)d_in[5];
    prm.W2  = (const float*)d_in[6];
    prm.b2  = (const float*)d_in[7];
    prm.W3  = (const float*)d_in[8];
    prm.b3  = (const float*)d_in[9];
    prm.Wu1 = (const float*)d_in[10];
    prm.bu1 = (const float*)d_in[11];
    prm.Wu2 = (const float*)d_in[12];
    prm.bu2 = (const float*)d_in[13];
    prm.Wu3 = (const float*)d_in[14];
    prm.bu3 = (const float*)d_in[15];
    prm.Wo  = (const float*)d_in[16];
    prm.bo  = (const float*)d_in[17];
    prm.out = (float*)d_out;

    short* Wp   = (short*)d_ws;                      // 33 * 262144 shorts (16.5 MB)
    short* W0p  = Wp + (size_t)33 * 262144;          // 8192 shorts
    short* WoP  = W0p + 8192;                        // 10 * 32768 shorts
    int* rowidx  = (int*)(WoP + (size_t)10 * 32768); // NB ints
    int* partial = rowidx + NB;                      // 16 * NDOM ints
    prm.Wp = Wp; prm.W0p = W0p; prm.WoP = WoP;
    prm.rowidx = rowidx; prm.partial = partial;

    void* args[] = { &prm };
    hipLaunchCooperativeKernel((void*)k_all, dim3(256), dim3(1024), args, 0, stream);
}